// Round 1
// baseline (652.483 us; speedup 1.0000x reference)
//
#include <hip/hip_runtime.h>
#include <hip/hip_bf16.h>
#include <math.h>

#define BQ 4
#define TQ 12
#define NQ 2000
#define EQ 32000
#define NDQ 16
#define EDQ 8
#define HQ 4
#define DQ 16
#define GQ 64
#define GHQ 64
#define NGQ 48          // B*T graphs
#define LN_EPSQ 1e-5f

// -------------------- CSR build (edge_index shared across graphs) ------------
__global__ void k_count(const int* __restrict__ ei, int* __restrict__ count) {
    int e = blockIdx.x * blockDim.x + threadIdx.x;
    if (e < EQ) atomicAdd(&count[ei[EQ + e]], 1);
}

__global__ void k_scan(const int* __restrict__ count, int* __restrict__ offs,
                       int* __restrict__ cursor) {
    __shared__ int buf[2][2048];
    int t = threadIdx.x;                       // 1024 threads
    for (int i = t; i < 2048; i += 1024)
        buf[0][i] = (i < NQ) ? count[i] : 0;
    __syncthreads();
    int src = 0;
    for (int sh = 1; sh < 2048; sh <<= 1) {
        int dst = src ^ 1;
        for (int i = t; i < 2048; i += 1024) {
            int v = buf[src][i];
            if (i >= sh) v += buf[src][i - sh];
            buf[dst][i] = v;
        }
        __syncthreads();
        src = dst;
    }
    for (int i = t; i <= NQ; i += 1024) {
        int off = (i == 0) ? 0 : buf[src][i - 1];
        offs[i] = off;
        if (i < NQ) cursor[i] = off;
    }
}

__global__ void k_scatter(const int* __restrict__ ei, int* __restrict__ cursor,
                          int* __restrict__ csr) {
    int e = blockIdx.x * blockDim.x + threadIdx.x;
    if (e < EQ) {
        int pos = atomicAdd(&cursor[ei[EQ + e]], 1);
        csr[pos] = e;
    }
}

// -------------------- node projection + per-node attn dots -------------------
// one wave (64 lanes) per (g,n); lane j computes h[g,n,j]
__global__ void k_nodeproj(const float* __restrict__ xf, const float* __restrict__ Wn,
                           const float* __restrict__ att,
                           float* __restrict__ hproj, float* __restrict__ sd,
                           float* __restrict__ ss) {
    __shared__ float Wl[NDQ * GQ];             // 16x64 = 4KB
    int t = threadIdx.x;
    for (int i = t; i < NDQ * GQ; i += blockDim.x) Wl[i] = Wn[i];
    __syncthreads();
    int wid = (blockIdx.x * blockDim.x + t) >> 6;   // g*NQ + n
    int lane = t & 63;
    if (wid >= NGQ * NQ) return;
    int g = wid / NQ, n = wid % NQ;
    const float* x = xf + ((size_t)g * NQ + n) * NDQ;
    float acc = 0.f;
#pragma unroll
    for (int i = 0; i < NDQ; ++i) acc = fmaf(x[i], Wl[i * GQ + lane], acc);
    hproj[((size_t)g * NQ + n) * GQ + lane] = acc;
    int hh = lane >> 4, d = lane & 15;
    float vd = acc * att[hh * 48 + d];
    float vs = acc * att[hh * 48 + 16 + d];
#pragma unroll
    for (int s = 8; s >= 1; s >>= 1) {
        vd += __shfl_xor(vd, s, 64);
        vs += __shfl_xor(vs, s, 64);
    }
    if (d == 0) {
        sd[((size_t)g * NQ + n) * HQ + hh] = vd;
        ss[((size_t)g * NQ + n) * HQ + hh] = vs;
    }
}

// -------------------- edge scores (factored s_e: 32 FMA/edge) ----------------
__global__ void k_edgescore(const float* __restrict__ ef, const float* __restrict__ We,
                            const float* __restrict__ att, const int* __restrict__ ei,
                            const float* __restrict__ sd, const float* __restrict__ ss,
                            float* __restrict__ score) {
    __shared__ float WA[EDQ * HQ];             // WA[i][h] = sum_d We[i][h*16+d]*a_e[h][d]
    int t = threadIdx.x;
    if (t < EDQ * HQ) {
        int i = t >> 2, hh = t & 3;
        float s = 0.f;
#pragma unroll
        for (int d = 0; d < DQ; ++d)
            s = fmaf(We[i * GQ + hh * DQ + d], att[hh * 48 + 32 + d], s);
        WA[t] = s;
    }
    __syncthreads();
    long gid = (long)blockIdx.x * blockDim.x + t;
    if (gid >= (long)NGQ * EQ) return;
    int g = (int)(gid / EQ), e = (int)(gid % EQ);
    const float4* ea4 = (const float4*)(ef + ((size_t)g * EQ + e) * EDQ);
    float4 a = ea4[0], b = ea4[1];
    float eav[8] = {a.x, a.y, a.z, a.w, b.x, b.y, b.z, b.w};
    float se[4] = {0.f, 0.f, 0.f, 0.f};
#pragma unroll
    for (int i = 0; i < 8; ++i)
#pragma unroll
        for (int hh = 0; hh < 4; ++hh)
            se[hh] = fmaf(eav[i], WA[i * 4 + hh], se[hh]);
    int s = ei[e], dd = ei[EQ + e];
    const float* sdp = sd + ((size_t)g * NQ + dd) * HQ;
    const float* ssp = ss + ((size_t)g * NQ + s) * HQ;
    float4 out;
    float* op = (float*)&out;
#pragma unroll
    for (int hh = 0; hh < 4; ++hh) {
        float sc = sdp[hh] + ssp[hh] + se[hh];
        op[hh] = (sc >= 0.f) ? sc : 0.2f * sc;
    }
    *(float4*)&score[((size_t)g * EQ + e) * HQ] = out;
}

// -------------------- per-node softmax over incoming edges (gather) ----------
__global__ void k_softmax(const int* __restrict__ offs, const int* __restrict__ csr,
                          float* __restrict__ score) {
    int gid = blockIdx.x * blockDim.x + threadIdx.x;   // g*(N*H) + n*H + h
    if (gid >= NGQ * NQ * HQ) return;
    int hh = gid & 3;
    int n = (gid >> 2) % NQ;
    int g = gid / (NQ * HQ);
    int beg = offs[n], end = offs[n + 1];
    size_t base = (size_t)g * EQ * HQ;
    float m = -1e30f;
    for (int s = beg; s < end; ++s)
        m = fmaxf(m, score[base + csr[s] * HQ + hh]);
    float sum = 0.f;
    for (int s = beg; s < end; ++s)
        sum += expf(score[base + csr[s] * HQ + hh] - m);
    float inv = 1.f / (sum + 1e-16f);
    for (int s = beg; s < end; ++s) {
        size_t idx = base + csr[s] * HQ + hh;
        score[idx] = expf(score[idx] - m) * inv;       // score becomes alpha
    }
}

// -------------------- aggregate + ELU + LayerNorm (one wave / node) ----------
__global__ void k_aggregate(const float* __restrict__ ef, const float* __restrict__ We,
                            const int* __restrict__ ei, const int* __restrict__ offs,
                            const int* __restrict__ csr,
                            const float* __restrict__ hproj, const float* __restrict__ alpha,
                            const float* __restrict__ gamma, const float* __restrict__ beta,
                            float* __restrict__ spatial) {
    __shared__ float Wl[EDQ * GQ];             // 8x64 = 2KB
    int t = threadIdx.x;
    for (int i = t; i < EDQ * GQ; i += blockDim.x) Wl[i] = We[i];
    __syncthreads();
    int wid = (blockIdx.x * blockDim.x + t) >> 6;
    int lane = t & 63;
    if (wid >= NGQ * NQ) return;
    int g = wid / NQ, n = wid % NQ;
    int beg = offs[n], end = offs[n + 1];
    float acc = 0.f;
    for (int s = beg; s < end; ++s) {
        int eid = csr[s];
        int src = ei[eid];
        float a = alpha[((size_t)g * EQ + eid) * HQ + (lane >> 4)];
        float hv = hproj[((size_t)g * NQ + src) * GQ + lane];
        const float* ea = ef + ((size_t)g * EQ + eid) * EDQ;
        float ep = 0.f;
#pragma unroll
        for (int i = 0; i < 8; ++i) ep = fmaf(ea[i], Wl[i * GQ + lane], ep);
        acc = fmaf(a, hv + ep, acc);
    }
    float x = (acc > 0.f) ? acc : (expf(acc) - 1.f);   // ELU
    float sum = x, sumsq = x * x;
#pragma unroll
    for (int s = 32; s >= 1; s >>= 1) {
        sum += __shfl_xor(sum, s, 64);
        sumsq += __shfl_xor(sumsq, s, 64);
    }
    float mu = sum * (1.f / 64.f);
    float var = sumsq * (1.f / 64.f) - mu * mu;
    float y = (x - mu) * rsqrtf(var + LN_EPSQ) * gamma[lane] + beta[lane];
    spatial[((size_t)g * NQ + n) * GQ + lane] = y;
}

// -------------------- GRU over T=12 + head (wave per (b,n), 4 waves/block) ---
__global__ void __launch_bounds__(256) k_gru(const float* __restrict__ spatial,
                       const float* __restrict__ Wih, const float* __restrict__ Whh,
                       const float* __restrict__ bih, const float* __restrict__ bhh,
                       const float* __restrict__ Wout, const float* __restrict__ bout,
                       float* __restrict__ out) {
    __shared__ __hip_bfloat16 wi[192][66];     // +2 pad: bank = (j + i/2) % 32
    __shared__ __hip_bfloat16 wh[192][66];
    __shared__ float xs[4][64], hs[4][64];
    int tid = threadIdx.x;
    for (int idx = tid; idx < 192 * 64; idx += 256) {
        int k = idx >> 6, j = idx & 63;
        wi[k][j] = __float2bfloat16(Wih[idx]);
        wh[k][j] = __float2bfloat16(Whh[idx]);
    }
    int w = tid >> 6, j = tid & 63;
    int id = blockIdx.x * 4 + w;               // b*NQ + n
    int b = id / NQ, n = id % NQ;
    float bi_r = bih[j], bi_z = bih[64 + j], bi_n = bih[128 + j];
    float bh_r = bhh[j], bh_z = bhh[64 + j], bh_n = bhh[128 + j];
    float h = 0.f;
    hs[w][j] = 0.f;
    __syncthreads();
    for (int t = 0; t < TQ; ++t) {
        xs[w][j] = spatial[(((size_t)b * TQ + t) * NQ + n) * GQ + j];
        __syncthreads();
        float ir = bi_r, iz = bi_z, in_ = bi_n, hr = bh_r, hz = bh_z, hn = bh_n;
#pragma unroll 8
        for (int i = 0; i < 64; ++i) {
            float xv = xs[w][i], hv = hs[w][i];
            ir  = fmaf(xv, __bfloat162float(wi[j][i]),       ir);
            iz  = fmaf(xv, __bfloat162float(wi[64 + j][i]),  iz);
            in_ = fmaf(xv, __bfloat162float(wi[128 + j][i]), in_);
            hr  = fmaf(hv, __bfloat162float(wh[j][i]),       hr);
            hz  = fmaf(hv, __bfloat162float(wh[64 + j][i]),  hz);
            hn  = fmaf(hv, __bfloat162float(wh[128 + j][i]), hn);
        }
        float r = 1.f / (1.f + expf(-(ir + hr)));
        float z = 1.f / (1.f + expf(-(iz + hz)));
        float nn = tanhf(in_ + r * hn);
        h = (1.f - z) * nn + z * h;
        __syncthreads();
        hs[w][j] = h;
        __syncthreads();
    }
    out[8000 + ((size_t)b * NQ + n) * GHQ + j] = h;    // h_i
    float pv = h * Wout[j];
#pragma unroll
    for (int s = 32; s >= 1; s >>= 1) pv += __shfl_xor(pv, s, 64);
    if (j == 0) out[(size_t)b * NQ + n] = pv + bout[0];  // pred
}

// -------------------- attention mean over batch ------------------------------
__global__ void k_attn(const float* __restrict__ alpha, float* __restrict__ out) {
    int gid = blockIdx.x * blockDim.x + threadIdx.x;   // t*EQ + e
    if (gid >= TQ * EQ) return;
    int tt = gid / EQ, e = gid % EQ;
    float ax = 0.f, ay = 0.f, az = 0.f, aw = 0.f;
#pragma unroll
    for (int b = 0; b < BQ; ++b) {
        float4 v = *(const float4*)&alpha[(((size_t)b * TQ + tt) * EQ + e) * HQ];
        ax += v.x; ay += v.y; az += v.z; aw += v.w;
    }
    float4 r = {ax * 0.25f, ay * 0.25f, az * 0.25f, aw * 0.25f};
    *(float4*)&out[520000 + (size_t)gid * HQ] = r;     // pred(8000)+h_i(512000)
}

extern "C" void kernel_launch(void* const* d_in, const int* in_sizes, int n_in,
                              void* d_out, int out_size, void* d_ws, size_t ws_size,
                              hipStream_t stream) {
    const float* nodef = (const float*)d_in[0];
    const float* edgef = (const float*)d_in[1];
    const float* Wn    = (const float*)d_in[2];
    const float* We    = (const float*)d_in[3];
    const float* att   = (const float*)d_in[4];
    const float* gamma = (const float*)d_in[5];
    const float* beta  = (const float*)d_in[6];
    const float* Wih   = (const float*)d_in[7];
    const float* Whh   = (const float*)d_in[8];
    const float* bih   = (const float*)d_in[9];
    const float* bhh   = (const float*)d_in[10];
    const float* Wout  = (const float*)d_in[11];
    const float* bout  = (const float*)d_in[12];
    const int*   ei    = (const int*)d_in[13];

    char* ws = (char*)d_ws;
    size_t o = 0;
    int* count  = (int*)(ws + o); o += 2048 * 4;
    int* offs   = (int*)(ws + o); o += 2048 * 4;
    int* cursor = (int*)(ws + o); o += 2048 * 4;
    int* csr    = (int*)(ws + o); o += 32768 * 4;
    float* hproj   = (float*)(ws + o); o += (size_t)NGQ * NQ * GQ * 4;
    float* sd      = (float*)(ws + o); o += (size_t)NGQ * NQ * HQ * 4;
    float* ss      = (float*)(ws + o); o += (size_t)NGQ * NQ * HQ * 4;
    float* score   = (float*)(ws + o); o += (size_t)NGQ * EQ * HQ * 4;
    float* spatial = (float*)(ws + o); o += (size_t)NGQ * NQ * GQ * 4;

    hipMemsetAsync(count, 0, NQ * sizeof(int), stream);
    k_count  <<<(EQ + 255) / 256, 256, 0, stream>>>(ei, count);
    k_scan   <<<1, 1024, 0, stream>>>(count, offs, cursor);
    k_scatter<<<(EQ + 255) / 256, 256, 0, stream>>>(ei, cursor, csr);

    k_nodeproj <<<(NGQ * NQ * 64) / 256, 256, 0, stream>>>(nodef, Wn, att, hproj, sd, ss);
    k_edgescore<<<((long)NGQ * EQ + 255) / 256, 256, 0, stream>>>(edgef, We, att, ei, sd, ss, score);
    k_softmax  <<<(NGQ * NQ * HQ + 255) / 256, 256, 0, stream>>>(offs, csr, score);
    k_aggregate<<<(NGQ * NQ * 64) / 256, 256, 0, stream>>>(edgef, We, ei, offs, csr,
                                                           hproj, score, gamma, beta, spatial);
    k_gru      <<<(BQ * NQ) / 4, 256, 0, stream>>>(spatial, Wih, Whh, bih, bhh, Wout, bout,
                                                   (float*)d_out);
    k_attn     <<<(TQ * EQ + 255) / 256, 256, 0, stream>>>(score, (float*)d_out);
}

// Round 2
// 481.886 us; speedup vs baseline: 1.3540x; 1.3540x over previous
//
#include <hip/hip_runtime.h>
#include <hip/hip_bf16.h>
#include <math.h>
#include <stdint.h>

#define BQ 4
#define TQ 12
#define NQ 2000
#define EQ 32000
#define NDQ 16
#define EDQ 8
#define HQ 4
#define DQ 16
#define GQ 64
#define GHQ 64
#define NGQ 48          // B*T graphs
#define LN_EPSQ 1e-5f
#define CCAP 128        // LDS edge cache per node (deg>CCAP falls back to global)

// -------------------- CSR build (edge_index shared across graphs) ------------
__global__ void k_count(const int* __restrict__ ei, int* __restrict__ count) {
    int e = blockIdx.x * blockDim.x + threadIdx.x;
    if (e < EQ) atomicAdd(&count[ei[EQ + e]], 1);
}

__global__ void k_scan(const int* __restrict__ count, int* __restrict__ offs,
                       int* __restrict__ cursor) {
    __shared__ int buf[2][2048];
    int t = threadIdx.x;                       // 1024 threads
    for (int i = t; i < 2048; i += 1024)
        buf[0][i] = (i < NQ) ? count[i] : 0;
    __syncthreads();
    int src = 0;
    for (int sh = 1; sh < 2048; sh <<= 1) {
        int dst = src ^ 1;
        for (int i = t; i < 2048; i += 1024) {
            int v = buf[src][i];
            if (i >= sh) v += buf[src][i - sh];
            buf[dst][i] = v;
        }
        __syncthreads();
        src = dst;
    }
    for (int i = t; i <= NQ; i += 1024) {
        int off = (i == 0) ? 0 : buf[src][i - 1];
        offs[i] = off;
        if (i < NQ) cursor[i] = off;
    }
}

__global__ void k_scatter(const int* __restrict__ ei, int* __restrict__ cursor,
                          int2* __restrict__ csr2) {
    int e = blockIdx.x * blockDim.x + threadIdx.x;
    if (e < EQ) {
        int pos = atomicAdd(&cursor[ei[EQ + e]], 1);
        csr2[pos] = make_int2(e, ei[e]);       // (eid, src)
    }
}

// -------------------- node projection + per-node attn dots -------------------
__global__ void k_nodeproj(const float* __restrict__ xf, const float* __restrict__ Wn,
                           const float* __restrict__ att,
                           float* __restrict__ hproj, float* __restrict__ sd,
                           float* __restrict__ ss) {
    __shared__ float Wl[NDQ * GQ];             // 16x64 = 4KB
    int t = threadIdx.x;
    for (int i = t; i < NDQ * GQ; i += blockDim.x) Wl[i] = Wn[i];
    __syncthreads();
    int wid = (blockIdx.x * blockDim.x + t) >> 6;   // g*NQ + n
    int lane = t & 63;
    int g = wid / NQ, n = wid % NQ;
    const float* x = xf + ((size_t)g * NQ + n) * NDQ;
    float acc = 0.f;
#pragma unroll
    for (int i = 0; i < NDQ; ++i) acc = fmaf(x[i], Wl[i * GQ + lane], acc);
    hproj[((size_t)g * NQ + n) * GQ + lane] = acc;
    int hh = lane >> 4, d = lane & 15;
    float vd = acc * att[hh * 48 + d];
    float vs = acc * att[hh * 48 + 16 + d];
#pragma unroll
    for (int s = 8; s >= 1; s >>= 1) {
        vd += __shfl_xor(vd, s, 64);
        vs += __shfl_xor(vs, s, 64);
    }
    if (d == 0) {
        sd[((size_t)g * NQ + n) * HQ + hh] = vd;
        ss[((size_t)g * NQ + n) * HQ + hh] = vs;
    }
}

// ------ fused: edge-score + softmax + aggregate + ELU + LN (wave per node) ---
// lanes in phase A: h = lane>>4, c = lane&15 (16 edges in parallel per h)
// lanes in phase B: lane = output feature j (h = j>>4)
__global__ void __launch_bounds__(256) k_fused(
        const float* __restrict__ ef, const float* __restrict__ We,
        const float* __restrict__ att,
        const int* __restrict__ offs, const int2* __restrict__ csr2,
        const float* __restrict__ sd, const float* __restrict__ ss,
        const float* __restrict__ hproj,
        const float* __restrict__ gamma, const float* __restrict__ beta,
        float* __restrict__ alphaG, float* __restrict__ spatial) {
    __shared__ float Wl[EDQ * GQ];             // 2KB: We staged
    __shared__ float WA[EDQ * HQ];             // factored edge-attn weights
    __shared__ float ecache[4][CCAP * 4];      // 8KB: exp values per (edge,h)
    __shared__ int   srcs[4][CCAP];            // 2KB: src node per edge
    __shared__ float wsum_s[4][32];            // [wave][h*8+i], inv-scaled
    __shared__ float hp[4][8];                 // [wave][h*2 + {mx,inv}]
    int t = threadIdx.x;
    for (int i = t; i < EDQ * GQ; i += 256) Wl[i] = We[i];
    if (t < EDQ * HQ) {
        int i = t >> 2, h4 = t & 3;
        float s = 0.f;
#pragma unroll
        for (int d = 0; d < DQ; ++d)
            s = fmaf(We[i * GQ + h4 * DQ + d], att[h4 * 48 + 32 + d], s);
        WA[t] = s;
    }
    __syncthreads();
    int w = t >> 6, lane = t & 63;
    int wid = blockIdx.x * 4 + w;              // exact: grid = NGQ*NQ/4
    int g = wid / NQ, n = wid % NQ;
    int beg = offs[n], deg = offs[n + 1] - beg;
    int h = lane >> 4, c = lane & 15;
    size_t ebase = (size_t)g * EQ;
    size_t nbase = (size_t)g * NQ;
    float sdv = sd[(nbase + n) * HQ + h];
    // ---- pass 1: compute scores, cache, max --------------------------------
    float mx = -1e30f;
    for (int k = c; k < deg; k += 16) {
        int2 pr = csr2[beg + k];
        float sse = ss[(nbase + pr.y) * HQ + h];
        const float4* ea4 = (const float4*)(ef + (ebase + pr.x) * EDQ);
        float4 lo = ea4[0], hi4 = ea4[1];
        float se = lo.x * WA[0 + h] + lo.y * WA[4 + h] + lo.z * WA[8 + h] + lo.w * WA[12 + h]
                 + hi4.x * WA[16 + h] + hi4.y * WA[20 + h] + hi4.z * WA[24 + h] + hi4.w * WA[28 + h];
        float sc = sdv + sse + se;
        sc = (sc >= 0.f) ? sc : 0.2f * sc;
        if (k < CCAP) {
            ecache[w][k * 4 + h] = sc;
            if (h == 0) srcs[w][k] = pr.y;
        }
        mx = fmaxf(mx, sc);
    }
#pragma unroll
    for (int s = 1; s < 16; s <<= 1) mx = fmaxf(mx, __shfl_xor(mx, s, 16));
    // ---- pass 2: exp, sum, weighted edge-feature sum -----------------------
    float sum = 0.f;
    float ws[8] = {0.f, 0.f, 0.f, 0.f, 0.f, 0.f, 0.f, 0.f};
    for (int k = c; k < deg; k += 16) {
        int2 pr = csr2[beg + k];
        float sc;
        if (k < CCAP) sc = ecache[w][k * 4 + h];
        else {
            float sse = ss[(nbase + pr.y) * HQ + h];
            const float4* ea4f = (const float4*)(ef + (ebase + pr.x) * EDQ);
            float4 lof = ea4f[0], hif = ea4f[1];
            float se = lof.x * WA[0 + h] + lof.y * WA[4 + h] + lof.z * WA[8 + h] + lof.w * WA[12 + h]
                     + hif.x * WA[16 + h] + hif.y * WA[20 + h] + hif.z * WA[24 + h] + hif.w * WA[28 + h];
            sc = sdv + sse + se;
            sc = (sc >= 0.f) ? sc : 0.2f * sc;
        }
        float e = __expf(sc - mx);
        if (k < CCAP) ecache[w][k * 4 + h] = e;
        sum += e;
        const float4* ea4 = (const float4*)(ef + (ebase + pr.x) * EDQ);
        float4 lo = ea4[0], hi4 = ea4[1];
        ws[0] = fmaf(e, lo.x, ws[0]); ws[1] = fmaf(e, lo.y, ws[1]);
        ws[2] = fmaf(e, lo.z, ws[2]); ws[3] = fmaf(e, lo.w, ws[3]);
        ws[4] = fmaf(e, hi4.x, ws[4]); ws[5] = fmaf(e, hi4.y, ws[5]);
        ws[6] = fmaf(e, hi4.z, ws[6]); ws[7] = fmaf(e, hi4.w, ws[7]);
    }
#pragma unroll
    for (int s = 1; s < 16; s <<= 1) sum += __shfl_xor(sum, s, 16);
    float inv = 1.f / (sum + 1e-16f);
#pragma unroll
    for (int i = 0; i < 8; ++i)
#pragma unroll
        for (int s = 1; s < 16; s <<= 1) ws[i] += __shfl_xor(ws[i], s, 16);
    if (c == 0) {
#pragma unroll
        for (int i = 0; i < 8; ++i) wsum_s[w][h * 8 + i] = ws[i] * inv;
        hp[w][h * 2] = mx; hp[w][h * 2 + 1] = inv;
    }
    // ---- pass 3: write normalized alpha to global --------------------------
    for (int k = c; k < deg; k += 16) {
        int2 pr = csr2[beg + k];
        float e;
        if (k < CCAP) e = ecache[w][k * 4 + h];
        else {
            float sse = ss[(nbase + pr.y) * HQ + h];
            const float4* ea4 = (const float4*)(ef + (ebase + pr.x) * EDQ);
            float4 lo = ea4[0], hi4 = ea4[1];
            float se = lo.x * WA[0 + h] + lo.y * WA[4 + h] + lo.z * WA[8 + h] + lo.w * WA[12 + h]
                     + hi4.x * WA[16 + h] + hi4.y * WA[20 + h] + hi4.z * WA[24 + h] + hi4.w * WA[28 + h];
            float sc = sdv + sse + se;
            sc = (sc >= 0.f) ? sc : 0.2f * sc;
            e = __expf(sc - mx);
        }
        alphaG[(ebase + pr.x) * HQ + h] = e * inv;
    }
    __syncthreads();
    // ---- phase B: aggregate alpha*h[src], unrolled x4 for MLP --------------
    int dmain = deg < CCAP ? deg : CCAP;
    float acc = 0.f;
    int k = 0;
    for (; k + 4 <= dmain; k += 4) {
        float e0 = ecache[w][(k + 0) * 4 + h];
        float e1 = ecache[w][(k + 1) * 4 + h];
        float e2 = ecache[w][(k + 2) * 4 + h];
        float e3 = ecache[w][(k + 3) * 4 + h];
        int s0 = srcs[w][k + 0], s1 = srcs[w][k + 1];
        int s2 = srcs[w][k + 2], s3 = srcs[w][k + 3];
        float h0 = hproj[(nbase + s0) * GQ + lane];
        float h1 = hproj[(nbase + s1) * GQ + lane];
        float h2 = hproj[(nbase + s2) * GQ + lane];
        float h3 = hproj[(nbase + s3) * GQ + lane];
        acc = fmaf(e0, h0, acc); acc = fmaf(e1, h1, acc);
        acc = fmaf(e2, h2, acc); acc = fmaf(e3, h3, acc);
    }
    for (; k < dmain; ++k) {
        float e0 = ecache[w][k * 4 + h];
        float h0 = hproj[(nbase + srcs[w][k]) * GQ + lane];
        acc = fmaf(e0, h0, acc);
    }
    for (; k < deg; ++k) {                     // cold path: deg > CCAP
        int2 pr = csr2[beg + k];
        float sse = ss[(nbase + pr.y) * HQ + h];
        const float4* ea4 = (const float4*)(ef + (ebase + pr.x) * EDQ);
        float4 lo = ea4[0], hi4 = ea4[1];
        float se = lo.x * WA[0 + h] + lo.y * WA[4 + h] + lo.z * WA[8 + h] + lo.w * WA[12 + h]
                 + hi4.x * WA[16 + h] + hi4.y * WA[20 + h] + hi4.z * WA[24 + h] + hi4.w * WA[28 + h];
        float sc = sdv + sse + se;
        sc = (sc >= 0.f) ? sc : 0.2f * sc;
        float e0 = __expf(sc - hp[w][h * 2]);
        float h0 = hproj[(nbase + pr.y) * GQ + lane];
        acc = fmaf(e0, h0, acc);
    }
    acc *= hp[w][h * 2 + 1];
    float t2 = 0.f;
#pragma unroll
    for (int i = 0; i < 8; ++i) t2 = fmaf(wsum_s[w][h * 8 + i], Wl[i * GQ + lane], t2);
    float x = acc + t2;
    x = (x > 0.f) ? x : (__expf(x) - 1.f);     // ELU
    float s1 = x, s2v = x * x;
#pragma unroll
    for (int s = 32; s >= 1; s >>= 1) {
        s1 += __shfl_xor(s1, s, 64);
        s2v += __shfl_xor(s2v, s, 64);
    }
    float mu = s1 * (1.f / 64.f);
    float var = s2v * (1.f / 64.f) - mu * mu;
    float y = (x - mu) * rsqrtf(var + LN_EPSQ) * gamma[lane] + beta[lane];
    spatial[(nbase + n) * GQ + lane] = y;
}

// -------------------- GRU (bf16x2-packed weights, 4 seqs/wave) ---------------
__device__ inline uint32_t f2bf(float f) {
    uint32_t u = __float_as_uint(f);
    return (u + 0x7fffu + ((u >> 16) & 1u)) >> 16;
}
__device__ inline float blo(uint32_t u) { return __uint_as_float(u << 16); }
__device__ inline float bhi(uint32_t u) { return __uint_as_float(u & 0xffff0000u); }

__global__ void __launch_bounds__(256) k_gru(const float* __restrict__ spatial,
                       const float* __restrict__ Wih, const float* __restrict__ Whh,
                       const float* __restrict__ bih, const float* __restrict__ bhh,
                       const float* __restrict__ Wout, const float* __restrict__ bout,
                       float* __restrict__ out) {
    __shared__ uint32_t wi2[192][35];          // pairs over i, pad 35: bank=(3j+p)%32
    __shared__ uint32_t wh2[192][35];
    __shared__ __align__(8) float xs[4][64];
    __shared__ __align__(8) float hs[4][64];
    int t = threadIdx.x;
    for (int idx = t; idx < 192 * 32; idx += 256) {
        int row = idx >> 5, p = idx & 31;
        float2 wv = *(const float2*)&Wih[row * 64 + 2 * p];
        wi2[row][p] = f2bf(wv.x) | (f2bf(wv.y) << 16);
        float2 vv = *(const float2*)&Whh[row * 64 + 2 * p];
        wh2[row][p] = f2bf(vv.x) | (f2bf(vv.y) << 16);
    }
    int w = t >> 6, j = t & 63;
    float bi_r = bih[j], bi_z = bih[64 + j], bi_n = bih[128 + j];
    float bh_r = bhh[j], bh_z = bhh[64 + j], bh_n = bhh[128 + j];
    float wo = Wout[j], bo = bout[0];
    __syncthreads();
    for (int rep = 0; rep < 4; ++rep) {
        int id = blockIdx.x * 16 + w * 4 + rep;    // b*NQ + n
        int b = id / NQ, n = id % NQ;
        float h = 0.f;
        hs[w][j] = 0.f;
        float xnext = spatial[(((size_t)b * TQ) * NQ + n) * GQ + j];
        __syncthreads();
        for (int tt = 0; tt < TQ; ++tt) {
            xs[w][j] = xnext;
            __syncthreads();
            if (tt + 1 < TQ)
                xnext = spatial[(((size_t)b * TQ + tt + 1) * NQ + n) * GQ + j];
            float ir = bi_r, iz = bi_z, in_ = bi_n, hr = bh_r, hz = bh_z, hn = bh_n;
#pragma unroll
            for (int p = 0; p < 32; ++p) {
                float2 xv = *(const float2*)&xs[w][2 * p];
                float2 hv = *(const float2*)&hs[w][2 * p];
                uint32_t a0 = wi2[j][p], a1 = wi2[64 + j][p], a2 = wi2[128 + j][p];
                uint32_t b0 = wh2[j][p], b1 = wh2[64 + j][p], b2 = wh2[128 + j][p];
                ir  = fmaf(xv.x, blo(a0), ir);  ir  = fmaf(xv.y, bhi(a0), ir);
                iz  = fmaf(xv.x, blo(a1), iz);  iz  = fmaf(xv.y, bhi(a1), iz);
                in_ = fmaf(xv.x, blo(a2), in_); in_ = fmaf(xv.y, bhi(a2), in_);
                hr  = fmaf(hv.x, blo(b0), hr);  hr  = fmaf(hv.y, bhi(b0), hr);
                hz  = fmaf(hv.x, blo(b1), hz);  hz  = fmaf(hv.y, bhi(b1), hz);
                hn  = fmaf(hv.x, blo(b2), hn);  hn  = fmaf(hv.y, bhi(b2), hn);
            }
            float r = 1.f / (1.f + __expf(-(ir + hr)));
            float z = 1.f / (1.f + __expf(-(iz + hz)));
            float nn = tanhf(in_ + r * hn);
            h = (1.f - z) * nn + z * h;
            __syncthreads();
            hs[w][j] = h;
        }
        out[8000 + ((size_t)b * NQ + n) * GHQ + j] = h;    // h_i
        float pv = h * wo;
#pragma unroll
        for (int s = 32; s >= 1; s >>= 1) pv += __shfl_xor(pv, s, 64);
        if (j == 0) out[(size_t)b * NQ + n] = pv + bo;     // pred
        __syncthreads();
    }
}

// -------------------- attention mean over batch ------------------------------
__global__ void k_attn(const float* __restrict__ alpha, float* __restrict__ out) {
    int gid = blockIdx.x * blockDim.x + threadIdx.x;   // t*EQ + e
    if (gid >= TQ * EQ) return;
    int tt = gid / EQ, e = gid % EQ;
    float ax = 0.f, ay = 0.f, az = 0.f, aw = 0.f;
#pragma unroll
    for (int b = 0; b < BQ; ++b) {
        float4 v = *(const float4*)&alpha[(((size_t)b * TQ + tt) * EQ + e) * HQ];
        ax += v.x; ay += v.y; az += v.z; aw += v.w;
    }
    float4 r = {ax * 0.25f, ay * 0.25f, az * 0.25f, aw * 0.25f};
    *(float4*)&out[520000 + (size_t)gid * HQ] = r;     // pred(8000)+h_i(512000)
}

extern "C" void kernel_launch(void* const* d_in, const int* in_sizes, int n_in,
                              void* d_out, int out_size, void* d_ws, size_t ws_size,
                              hipStream_t stream) {
    const float* nodef = (const float*)d_in[0];
    const float* edgef = (const float*)d_in[1];
    const float* Wn    = (const float*)d_in[2];
    const float* We    = (const float*)d_in[3];
    const float* att   = (const float*)d_in[4];
    const float* gamma = (const float*)d_in[5];
    const float* beta  = (const float*)d_in[6];
    const float* Wih   = (const float*)d_in[7];
    const float* Whh   = (const float*)d_in[8];
    const float* bih   = (const float*)d_in[9];
    const float* bhh   = (const float*)d_in[10];
    const float* Wout  = (const float*)d_in[11];
    const float* bout  = (const float*)d_in[12];
    const int*   ei    = (const int*)d_in[13];

    char* ws = (char*)d_ws;
    size_t o = 0;
    int*  count  = (int*)(ws + o);  o += 2048 * 4;
    int*  offs   = (int*)(ws + o);  o += 2048 * 4;
    int*  cursor = (int*)(ws + o);  o += 2048 * 4;
    int2* csr2   = (int2*)(ws + o); o += (size_t)EQ * 8;
    float* hproj   = (float*)(ws + o); o += (size_t)NGQ * NQ * GQ * 4;
    float* sd      = (float*)(ws + o); o += (size_t)NGQ * NQ * HQ * 4;
    float* ss      = (float*)(ws + o); o += (size_t)NGQ * NQ * HQ * 4;
    float* alphaG  = (float*)(ws + o); o += (size_t)NGQ * EQ * HQ * 4;
    float* spatial = (float*)(ws + o); o += (size_t)NGQ * NQ * GQ * 4;

    hipMemsetAsync(count, 0, NQ * sizeof(int), stream);
    k_count  <<<(EQ + 255) / 256, 256, 0, stream>>>(ei, count);
    k_scan   <<<1, 1024, 0, stream>>>(count, offs, cursor);
    k_scatter<<<(EQ + 255) / 256, 256, 0, stream>>>(ei, cursor, csr2);

    k_nodeproj<<<(NGQ * NQ * 64) / 256, 256, 0, stream>>>(nodef, Wn, att, hproj, sd, ss);
    k_fused   <<<(NGQ * NQ) / 4, 256, 0, stream>>>(edgef, We, att, offs, csr2,
                                                   sd, ss, hproj, gamma, beta,
                                                   alphaG, spatial);
    k_gru     <<<(BQ * NQ) / 16, 256, 0, stream>>>(spatial, Wih, Whh, bih, bhh,
                                                   Wout, bout, (float*)d_out);
    k_attn    <<<(TQ * EQ + 255) / 256, 256, 0, stream>>>(alphaG, (float*)d_out);
}

// Round 3
// 319.816 us; speedup vs baseline: 2.0402x; 1.5068x over previous
//
#include <hip/hip_runtime.h>
#include <hip/hip_bf16.h>
#include <math.h>
#include <stdint.h>

#define BQ 4
#define TQ 12
#define NQ 2000
#define EQ 32000
#define NDQ 16
#define EDQ 8
#define HQ 4
#define DQ 16
#define GQ 64
#define GHQ 64
#define NGQ 48          // B*T graphs
#define LN_EPSQ 1e-5f
#define CCAP 128        // LDS edge cache per node (deg>CCAP falls back to global)

typedef _Float16 half8 __attribute__((ext_vector_type(8)));
typedef float f32x4 __attribute__((ext_vector_type(4)));

// -------------------- CSR build (edge_index shared across graphs) ------------
__global__ void k_count(const int* __restrict__ ei, int* __restrict__ count) {
    int e = blockIdx.x * blockDim.x + threadIdx.x;
    if (e < EQ) atomicAdd(&count[ei[EQ + e]], 1);
}

__global__ void k_scan(const int* __restrict__ count, int* __restrict__ offs,
                       int* __restrict__ cursor) {
    __shared__ int buf[2][2048];
    int t = threadIdx.x;                       // 1024 threads
    for (int i = t; i < 2048; i += 1024)
        buf[0][i] = (i < NQ) ? count[i] : 0;
    __syncthreads();
    int src = 0;
    for (int sh = 1; sh < 2048; sh <<= 1) {
        int dst = src ^ 1;
        for (int i = t; i < 2048; i += 1024) {
            int v = buf[src][i];
            if (i >= sh) v += buf[src][i - sh];
            buf[dst][i] = v;
        }
        __syncthreads();
        src = dst;
    }
    for (int i = t; i <= NQ; i += 1024) {
        int off = (i == 0) ? 0 : buf[src][i - 1];
        offs[i] = off;
        if (i < NQ) cursor[i] = off;
    }
}

__global__ void k_scatter(const int* __restrict__ ei, int* __restrict__ cursor,
                          int2* __restrict__ csr2) {
    int e = blockIdx.x * blockDim.x + threadIdx.x;
    if (e < EQ) {
        int pos = atomicAdd(&cursor[ei[EQ + e]], 1);
        csr2[pos] = make_int2(e, ei[e]);       // (eid, src)
    }
}

// -------------------- node projection + per-node attn dots -------------------
__global__ void k_nodeproj(const float* __restrict__ xf, const float* __restrict__ Wn,
                           const float* __restrict__ att,
                           float* __restrict__ hproj, float* __restrict__ sd,
                           float* __restrict__ ss) {
    __shared__ float Wl[NDQ * GQ];             // 16x64 = 4KB
    int t = threadIdx.x;
    for (int i = t; i < NDQ * GQ; i += blockDim.x) Wl[i] = Wn[i];
    __syncthreads();
    int wid = (blockIdx.x * blockDim.x + t) >> 6;   // g*NQ + n
    int lane = t & 63;
    int g = wid / NQ, n = wid % NQ;
    const float* x = xf + ((size_t)g * NQ + n) * NDQ;
    float acc = 0.f;
#pragma unroll
    for (int i = 0; i < NDQ; ++i) acc = fmaf(x[i], Wl[i * GQ + lane], acc);
    hproj[((size_t)g * NQ + n) * GQ + lane] = acc;
    int hh = lane >> 4, d = lane & 15;
    float vd = acc * att[hh * 48 + d];
    float vs = acc * att[hh * 48 + 16 + d];
#pragma unroll
    for (int s = 8; s >= 1; s >>= 1) {
        vd += __shfl_xor(vd, s, 64);
        vs += __shfl_xor(vs, s, 64);
    }
    if (d == 0) {
        sd[((size_t)g * NQ + n) * HQ + hh] = vd;
        ss[((size_t)g * NQ + n) * HQ + hh] = vs;
    }
}

// ------ fused: edge-score + softmax + aggregate + ELU + LN (wave per node) ---
__global__ void __launch_bounds__(256) k_fused(
        const float* __restrict__ ef, const float* __restrict__ We,
        const float* __restrict__ att,
        const int* __restrict__ offs, const int2* __restrict__ csr2,
        const float* __restrict__ sd, const float* __restrict__ ss,
        const float* __restrict__ hproj,
        const float* __restrict__ gamma, const float* __restrict__ beta,
        float* __restrict__ alphaG, _Float16* __restrict__ spatialH) {
    __shared__ float Wl[EDQ * GQ];             // 2KB: We staged
    __shared__ float WA[EDQ * HQ];             // factored edge-attn weights
    __shared__ float ecache[4][CCAP * 4];      // 8KB: exp values per (edge,h)
    __shared__ int   srcs[4][CCAP];            // 2KB: src node per edge
    __shared__ float wsum_s[4][32];            // [wave][h*8+i], inv-scaled
    __shared__ float hp[4][8];                 // [wave][h*2 + {mx,inv}]
    int t = threadIdx.x;
    for (int i = t; i < EDQ * GQ; i += 256) Wl[i] = We[i];
    if (t < EDQ * HQ) {
        int i = t >> 2, h4 = t & 3;
        float s = 0.f;
#pragma unroll
        for (int d = 0; d < DQ; ++d)
            s = fmaf(We[i * GQ + h4 * DQ + d], att[h4 * 48 + 32 + d], s);
        WA[t] = s;
    }
    __syncthreads();
    int w = t >> 6, lane = t & 63;
    int wid = blockIdx.x * 4 + w;              // exact: grid = NGQ*NQ/4
    int g = wid / NQ, n = wid % NQ;
    int beg = offs[n], deg = offs[n + 1] - beg;
    int h = lane >> 4, c = lane & 15;
    size_t ebase = (size_t)g * EQ;
    size_t nbase = (size_t)g * NQ;
    float sdv = sd[(nbase + n) * HQ + h];
    // ---- pass 1: compute scores, cache, max --------------------------------
    float mx = -1e30f;
    for (int k = c; k < deg; k += 16) {
        int2 pr = csr2[beg + k];
        float sse = ss[(nbase + pr.y) * HQ + h];
        const float4* ea4 = (const float4*)(ef + (ebase + pr.x) * EDQ);
        float4 lo = ea4[0], hi4 = ea4[1];
        float se = lo.x * WA[0 + h] + lo.y * WA[4 + h] + lo.z * WA[8 + h] + lo.w * WA[12 + h]
                 + hi4.x * WA[16 + h] + hi4.y * WA[20 + h] + hi4.z * WA[24 + h] + hi4.w * WA[28 + h];
        float sc = sdv + sse + se;
        sc = (sc >= 0.f) ? sc : 0.2f * sc;
        if (k < CCAP) {
            ecache[w][k * 4 + h] = sc;
            if (h == 0) srcs[w][k] = pr.y;
        }
        mx = fmaxf(mx, sc);
    }
#pragma unroll
    for (int s = 1; s < 16; s <<= 1) mx = fmaxf(mx, __shfl_xor(mx, s, 16));
    // ---- pass 2: exp, sum, weighted edge-feature sum -----------------------
    float sum = 0.f;
    float ws[8] = {0.f, 0.f, 0.f, 0.f, 0.f, 0.f, 0.f, 0.f};
    for (int k = c; k < deg; k += 16) {
        int2 pr = csr2[beg + k];
        float sc;
        if (k < CCAP) sc = ecache[w][k * 4 + h];
        else {
            float sse = ss[(nbase + pr.y) * HQ + h];
            const float4* ea4f = (const float4*)(ef + (ebase + pr.x) * EDQ);
            float4 lof = ea4f[0], hif = ea4f[1];
            float se = lof.x * WA[0 + h] + lof.y * WA[4 + h] + lof.z * WA[8 + h] + lof.w * WA[12 + h]
                     + hif.x * WA[16 + h] + hif.y * WA[20 + h] + hif.z * WA[24 + h] + hif.w * WA[28 + h];
            sc = sdv + sse + se;
            sc = (sc >= 0.f) ? sc : 0.2f * sc;
        }
        float e = __expf(sc - mx);
        if (k < CCAP) ecache[w][k * 4 + h] = e;
        sum += e;
        const float4* ea4 = (const float4*)(ef + (ebase + pr.x) * EDQ);
        float4 lo = ea4[0], hi4 = ea4[1];
        ws[0] = fmaf(e, lo.x, ws[0]); ws[1] = fmaf(e, lo.y, ws[1]);
        ws[2] = fmaf(e, lo.z, ws[2]); ws[3] = fmaf(e, lo.w, ws[3]);
        ws[4] = fmaf(e, hi4.x, ws[4]); ws[5] = fmaf(e, hi4.y, ws[5]);
        ws[6] = fmaf(e, hi4.z, ws[6]); ws[7] = fmaf(e, hi4.w, ws[7]);
    }
#pragma unroll
    for (int s = 1; s < 16; s <<= 1) sum += __shfl_xor(sum, s, 16);
    float inv = 1.f / (sum + 1e-16f);
#pragma unroll
    for (int i = 0; i < 8; ++i)
#pragma unroll
        for (int s = 1; s < 16; s <<= 1) ws[i] += __shfl_xor(ws[i], s, 16);
    if (c == 0) {
#pragma unroll
        for (int i = 0; i < 8; ++i) wsum_s[w][h * 8 + i] = ws[i] * inv;
        hp[w][h * 2] = mx; hp[w][h * 2 + 1] = inv;
    }
    // ---- pass 3: write normalized alpha to global --------------------------
    for (int k = c; k < deg; k += 16) {
        int2 pr = csr2[beg + k];
        float e;
        if (k < CCAP) e = ecache[w][k * 4 + h];
        else {
            float sse = ss[(nbase + pr.y) * HQ + h];
            const float4* ea4 = (const float4*)(ef + (ebase + pr.x) * EDQ);
            float4 lo = ea4[0], hi4 = ea4[1];
            float se = lo.x * WA[0 + h] + lo.y * WA[4 + h] + lo.z * WA[8 + h] + lo.w * WA[12 + h]
                     + hi4.x * WA[16 + h] + hi4.y * WA[20 + h] + hi4.z * WA[24 + h] + hi4.w * WA[28 + h];
            float sc = sdv + sse + se;
            sc = (sc >= 0.f) ? sc : 0.2f * sc;
            e = __expf(sc - mx);
        }
        alphaG[(ebase + pr.x) * HQ + h] = e * inv;
    }
    __syncthreads();
    // ---- phase B: aggregate alpha*h[src], unrolled x4 for MLP --------------
    int dmain = deg < CCAP ? deg : CCAP;
    float acc = 0.f;
    int k = 0;
    for (; k + 4 <= dmain; k += 4) {
        float e0 = ecache[w][(k + 0) * 4 + h];
        float e1 = ecache[w][(k + 1) * 4 + h];
        float e2 = ecache[w][(k + 2) * 4 + h];
        float e3 = ecache[w][(k + 3) * 4 + h];
        int s0 = srcs[w][k + 0], s1 = srcs[w][k + 1];
        int s2 = srcs[w][k + 2], s3 = srcs[w][k + 3];
        float h0 = hproj[(nbase + s0) * GQ + lane];
        float h1 = hproj[(nbase + s1) * GQ + lane];
        float h2 = hproj[(nbase + s2) * GQ + lane];
        float h3 = hproj[(nbase + s3) * GQ + lane];
        acc = fmaf(e0, h0, acc); acc = fmaf(e1, h1, acc);
        acc = fmaf(e2, h2, acc); acc = fmaf(e3, h3, acc);
    }
    for (; k < dmain; ++k) {
        float e0 = ecache[w][k * 4 + h];
        float h0 = hproj[(nbase + srcs[w][k]) * GQ + lane];
        acc = fmaf(e0, h0, acc);
    }
    for (; k < deg; ++k) {                     // cold path: deg > CCAP
        int2 pr = csr2[beg + k];
        float sse = ss[(nbase + pr.y) * HQ + h];
        const float4* ea4 = (const float4*)(ef + (ebase + pr.x) * EDQ);
        float4 lo = ea4[0], hi4 = ea4[1];
        float se = lo.x * WA[0 + h] + lo.y * WA[4 + h] + lo.z * WA[8 + h] + lo.w * WA[12 + h]
                 + hi4.x * WA[16 + h] + hi4.y * WA[20 + h] + hi4.z * WA[24 + h] + hi4.w * WA[28 + h];
        float sc = sdv + sse + se;
        sc = (sc >= 0.f) ? sc : 0.2f * sc;
        float e0 = __expf(sc - hp[w][h * 2]);
        float h0 = hproj[(nbase + pr.y) * GQ + lane];
        acc = fmaf(e0, h0, acc);
    }
    acc *= hp[w][h * 2 + 1];
    float t2 = 0.f;
#pragma unroll
    for (int i = 0; i < 8; ++i) t2 = fmaf(wsum_s[w][h * 8 + i], Wl[i * GQ + lane], t2);
    float x = acc + t2;
    x = (x > 0.f) ? x : (__expf(x) - 1.f);     // ELU
    float s1 = x, s2v = x * x;
#pragma unroll
    for (int s = 32; s >= 1; s >>= 1) {
        s1 += __shfl_xor(s1, s, 64);
        s2v += __shfl_xor(s2v, s, 64);
    }
    float mu = s1 * (1.f / 64.f);
    float var = s2v * (1.f / 64.f) - mu * mu;
    float y = (x - mu) * rsqrtf(var + LN_EPSQ) * gamma[lane] + beta[lane];
    spatialH[(nbase + n) * GQ + lane] = (_Float16)y;
}

// -------------------- GRU via MFMA (f16 inputs, f32 accum) -------------------
// block = 32 sequences, 4 waves; wave w owns hidden cols [16w,16w+16)
// A-frag: lane l -> A[l%16][8*(l/16)+i]; C-frag: row=(l/16)*4+reg, col=l%16
__device__ inline f32x4 MF(half8 a, half8 b, f32x4 c) {
    return __builtin_amdgcn_mfma_f32_16x16x32_f16(a, b, c, 0, 0, 0);
}

__global__ void __launch_bounds__(256) k_gru(
        const _Float16* __restrict__ xh,     // [48][2000][64] f16 (g = b*12+t)
        const float* __restrict__ Wih, const float* __restrict__ Whh,
        const float* __restrict__ bih, const float* __restrict__ bhh,
        const float* __restrict__ Wout, const float* __restrict__ bout,
        float* __restrict__ out) {
    __shared__ _Float16 hlds[32][72];          // +8 pad: 144B row stride (16B-aligned)
    __shared__ float pred_s[4][32];
    int tid = threadIdx.x;
    int w = tid >> 6, l = tid & 63;
    int lr = l & 15, lg = l >> 4;
    int j = w * 16 + lr;                       // this lane's hidden/gate column
    // ---- weight B-fragments (f16, register-resident) -----------------------
    half8 wiF[3][2], whF[3][2];
#pragma unroll
    for (int gb = 0; gb < 3; ++gb) {
        int q = gb * 64 + j;                   // gate row of W (r/z/n blocks)
#pragma unroll
        for (int kt = 0; kt < 2; ++kt) {
            const float* p  = Wih + q * 64 + kt * 32 + lg * 8;
            const float* p2 = Whh + q * 64 + kt * 32 + lg * 8;
            half8 a, b;
#pragma unroll
            for (int i = 0; i < 8; ++i) { a[i] = (_Float16)p[i]; b[i] = (_Float16)p2[i]; }
            wiF[gb][kt] = a; whF[gb][kt] = b;
        }
    }
    float br  = bih[j] + bhh[j];
    float bz  = bih[64 + j] + bhh[64 + j];
    float bin = bih[128 + j];
    float bhn = bhh[128 + j];
    float wo  = Wout[j];
    for (int i = tid; i < 32 * 72; i += 256) ((_Float16*)hlds)[i] = (_Float16)0.f;
    // ---- per-lane x row pointers (A-side: row = sequence) -------------------
    int id0 = blockIdx.x * 32;
    const _Float16* xp0; const _Float16* xp1;
    {
        int id = id0 + lr;          int b = id / NQ, n = id - b * NQ;
        xp0 = xh + ((size_t)b * TQ * NQ + n) * GQ + lg * 8;
        int id2 = id0 + 16 + lr;    int b2 = id2 / NQ, n2 = id2 - b2 * NQ;
        xp1 = xh + ((size_t)b2 * TQ * NQ + n2) * GQ + lg * 8;
    }
    half8 xa[2][2];
    xa[0][0] = *(const half8*)xp0; xa[0][1] = *(const half8*)(xp0 + 32);
    xa[1][0] = *(const half8*)xp1; xa[1][1] = *(const half8*)(xp1 + 32);
    float hprev[2][4] = {{0.f,0.f,0.f,0.f},{0.f,0.f,0.f,0.f}};
    __syncthreads();
    for (int t = 0; t < TQ; ++t) {
        f32x4 aR[2], aZ[2], aIN[2], aHN[2];
#pragma unroll
        for (int mt = 0; mt < 2; ++mt) {
            aR[mt]  = (f32x4){br, br, br, br};
            aZ[mt]  = (f32x4){bz, bz, bz, bz};
            aIN[mt] = (f32x4){bin, bin, bin, bin};
            aHN[mt] = (f32x4){bhn, bhn, bhn, bhn};
        }
        // gi = x @ Wih^T
#pragma unroll
        for (int mt = 0; mt < 2; ++mt)
#pragma unroll
            for (int kt = 0; kt < 2; ++kt) {
                aR[mt]  = MF(xa[mt][kt], wiF[0][kt], aR[mt]);
                aZ[mt]  = MF(xa[mt][kt], wiF[1][kt], aZ[mt]);
                aIN[mt] = MF(xa[mt][kt], wiF[2][kt], aIN[mt]);
            }
        // h fragments from LDS
        half8 ha[2][2];
#pragma unroll
        for (int mt = 0; mt < 2; ++mt) {
            ha[mt][0] = *(const half8*)&hlds[16 * mt + lr][lg * 8];
            ha[mt][1] = *(const half8*)&hlds[16 * mt + lr][32 + lg * 8];
        }
        // gh = h @ Whh^T
#pragma unroll
        for (int mt = 0; mt < 2; ++mt)
#pragma unroll
            for (int kt = 0; kt < 2; ++kt) {
                aR[mt]  = MF(ha[mt][kt], whF[0][kt], aR[mt]);
                aZ[mt]  = MF(ha[mt][kt], whF[1][kt], aZ[mt]);
                aHN[mt] = MF(ha[mt][kt], whF[2][kt], aHN[mt]);
            }
        // prefetch next x
        if (t + 1 < TQ) {
            xp0 += (size_t)NQ * GQ; xp1 += (size_t)NQ * GQ;
            xa[0][0] = *(const half8*)xp0; xa[0][1] = *(const half8*)(xp0 + 32);
            xa[1][0] = *(const half8*)xp1; xa[1][1] = *(const half8*)(xp1 + 32);
        }
        // gates
#pragma unroll
        for (int mt = 0; mt < 2; ++mt)
#pragma unroll
            for (int r4 = 0; r4 < 4; ++r4) {
                float r = 1.f / (1.f + __expf(-aR[mt][r4]));
                float z = 1.f / (1.f + __expf(-aZ[mt][r4]));
                float xg = aIN[mt][r4] + r * aHN[mt][r4];
                float e2 = __expf(2.f * xg);
                float nn = 1.f - 2.f / (e2 + 1.f);     // tanh(xg)
                hprev[mt][r4] = z * (hprev[mt][r4] - nn) + nn;
            }
        __syncthreads();                       // all h reads done
#pragma unroll
        for (int mt = 0; mt < 2; ++mt)
#pragma unroll
            for (int r4 = 0; r4 < 4; ++r4)
                hlds[16 * mt + 4 * lg + r4][j] = (_Float16)hprev[mt][r4];
        __syncthreads();                       // h_t visible
    }
    // ---- outputs ------------------------------------------------------------
    float pv[2][4];
#pragma unroll
    for (int mt = 0; mt < 2; ++mt)
#pragma unroll
        for (int r4 = 0; r4 < 4; ++r4) {
            int id = id0 + 16 * mt + 4 * lg + r4;
            out[8000 + (size_t)id * GHQ + j] = hprev[mt][r4];
            pv[mt][r4] = hprev[mt][r4] * wo;
        }
#pragma unroll
    for (int s = 1; s <= 8; s <<= 1)
#pragma unroll
        for (int mt = 0; mt < 2; ++mt)
#pragma unroll
            for (int r4 = 0; r4 < 4; ++r4)
                pv[mt][r4] += __shfl_xor(pv[mt][r4], s);
    if (lr == 0) {
#pragma unroll
        for (int mt = 0; mt < 2; ++mt)
#pragma unroll
            for (int r4 = 0; r4 < 4; ++r4)
                pred_s[w][16 * mt + 4 * lg + r4] = pv[mt][r4];
    }
    __syncthreads();
    if (tid < 32) {
        float s = pred_s[0][tid] + pred_s[1][tid] + pred_s[2][tid] + pred_s[3][tid] + bout[0];
        out[id0 + tid] = s;
    }
}

// -------------------- attention mean over batch ------------------------------
__global__ void k_attn(const float* __restrict__ alpha, float* __restrict__ out) {
    int gid = blockIdx.x * blockDim.x + threadIdx.x;   // t*EQ + e
    if (gid >= TQ * EQ) return;
    int tt = gid / EQ, e = gid % EQ;
    float ax = 0.f, ay = 0.f, az = 0.f, aw = 0.f;
#pragma unroll
    for (int b = 0; b < BQ; ++b) {
        float4 v = *(const float4*)&alpha[(((size_t)b * TQ + tt) * EQ + e) * HQ];
        ax += v.x; ay += v.y; az += v.z; aw += v.w;
    }
    float4 r = {ax * 0.25f, ay * 0.25f, az * 0.25f, aw * 0.25f};
    *(float4*)&out[520000 + (size_t)gid * HQ] = r;     // pred(8000)+h_i(512000)
}

extern "C" void kernel_launch(void* const* d_in, const int* in_sizes, int n_in,
                              void* d_out, int out_size, void* d_ws, size_t ws_size,
                              hipStream_t stream) {
    const float* nodef = (const float*)d_in[0];
    const float* edgef = (const float*)d_in[1];
    const float* Wn    = (const float*)d_in[2];
    const float* We    = (const float*)d_in[3];
    const float* att   = (const float*)d_in[4];
    const float* gamma = (const float*)d_in[5];
    const float* beta  = (const float*)d_in[6];
    const float* Wih   = (const float*)d_in[7];
    const float* Whh   = (const float*)d_in[8];
    const float* bih   = (const float*)d_in[9];
    const float* bhh   = (const float*)d_in[10];
    const float* Wout  = (const float*)d_in[11];
    const float* bout  = (const float*)d_in[12];
    const int*   ei    = (const int*)d_in[13];

    char* ws = (char*)d_ws;
    size_t o = 0;
    int*  count  = (int*)(ws + o);  o += 2048 * 4;
    int*  offs   = (int*)(ws + o);  o += 2048 * 4;
    int*  cursor = (int*)(ws + o);  o += 2048 * 4;
    int2* csr2   = (int2*)(ws + o); o += (size_t)EQ * 8;
    float* hproj   = (float*)(ws + o); o += (size_t)NGQ * NQ * GQ * 4;
    float* sd      = (float*)(ws + o); o += (size_t)NGQ * NQ * HQ * 4;
    float* ss      = (float*)(ws + o); o += (size_t)NGQ * NQ * HQ * 4;
    float* alphaG  = (float*)(ws + o); o += (size_t)NGQ * EQ * HQ * 4;
    _Float16* spatialH = (_Float16*)(ws + o); o += (size_t)NGQ * NQ * GQ * 2;

    hipMemsetAsync(count, 0, NQ * sizeof(int), stream);
    k_count  <<<(EQ + 255) / 256, 256, 0, stream>>>(ei, count);
    k_scan   <<<1, 1024, 0, stream>>>(count, offs, cursor);
    k_scatter<<<(EQ + 255) / 256, 256, 0, stream>>>(ei, cursor, csr2);

    k_nodeproj<<<(NGQ * NQ * 64) / 256, 256, 0, stream>>>(nodef, Wn, att, hproj, sd, ss);
    k_fused   <<<(NGQ * NQ) / 4, 256, 0, stream>>>(edgef, We, att, offs, csr2,
                                                   sd, ss, hproj, gamma, beta,
                                                   alphaG, spatialH);
    k_gru     <<<(BQ * NQ) / 32, 256, 0, stream>>>(spatialH, Wih, Whh, bih, bhh,
                                                   Wout, bout, (float*)d_out);
    k_attn    <<<(TQ * EQ + 255) / 256, 256, 0, stream>>>(alphaG, (float*)d_out);
}

// Round 4
// 297.380 us; speedup vs baseline: 2.1941x; 1.0754x over previous
//
#include <hip/hip_runtime.h>
#include <hip/hip_bf16.h>
#include <math.h>
#include <stdint.h>

#define BQ 4
#define TQ 12
#define NQ 2000
#define EQ 32000
#define NDQ 16
#define EDQ 8
#define HQ 4
#define DQ 16
#define GQ 64
#define GHQ 64
#define NGQ 48          // B*T graphs
#define LN_EPSQ 1e-5f
#define CCAP 64         // LDS edge cache per node (deg>CCAP falls back to global)

typedef _Float16 half8 __attribute__((ext_vector_type(8)));
typedef _Float16 half4v __attribute__((ext_vector_type(4)));
typedef float f32x4 __attribute__((ext_vector_type(4)));

// -------------------- CSR build (edge_index shared across graphs) ------------
__global__ void k_count(const int* __restrict__ ei, int* __restrict__ count) {
    int e = blockIdx.x * blockDim.x + threadIdx.x;
    if (e < EQ) atomicAdd(&count[ei[EQ + e]], 1);
}

__global__ void k_scan(const int* __restrict__ count, int* __restrict__ offs,
                       int* __restrict__ cursor) {
    __shared__ int buf[2][2048];
    int t = threadIdx.x;                       // 1024 threads
    for (int i = t; i < 2048; i += 1024)
        buf[0][i] = (i < NQ) ? count[i] : 0;
    __syncthreads();
    int src = 0;
    for (int sh = 1; sh < 2048; sh <<= 1) {
        int dst = src ^ 1;
        for (int i = t; i < 2048; i += 1024) {
            int v = buf[src][i];
            if (i >= sh) v += buf[src][i - sh];
            buf[dst][i] = v;
        }
        __syncthreads();
        src = dst;
    }
    for (int i = t; i <= NQ; i += 1024) {
        int off = (i == 0) ? 0 : buf[src][i - 1];
        offs[i] = off;
        if (i < NQ) cursor[i] = off;
    }
}

__global__ void k_scatter(const int* __restrict__ ei, int* __restrict__ cursor,
                          int2* __restrict__ csr2) {
    int e = blockIdx.x * blockDim.x + threadIdx.x;
    if (e < EQ) {
        int pos = atomicAdd(&cursor[ei[EQ + e]], 1);
        csr2[pos] = make_int2(e, ei[e]);       // (eid, src)
    }
}

// -------------------- node projection + per-node attn dots -------------------
__global__ void k_nodeproj(const float* __restrict__ xf, const float* __restrict__ Wn,
                           const float* __restrict__ att,
                           _Float16* __restrict__ hprojH, float* __restrict__ sd,
                           float* __restrict__ ss) {
    __shared__ float Wl[NDQ * GQ];             // 16x64 = 4KB
    int t = threadIdx.x;
    for (int i = t; i < NDQ * GQ; i += blockDim.x) Wl[i] = Wn[i];
    __syncthreads();
    int wid = (blockIdx.x * blockDim.x + t) >> 6;   // g*NQ + n
    int lane = t & 63;
    int g = wid / NQ, n = wid % NQ;
    const float* x = xf + ((size_t)g * NQ + n) * NDQ;
    float acc = 0.f;
#pragma unroll
    for (int i = 0; i < NDQ; ++i) acc = fmaf(x[i], Wl[i * GQ + lane], acc);
    hprojH[((size_t)g * NQ + n) * GQ + lane] = (_Float16)acc;
    int hh = lane >> 4, d = lane & 15;
    float vd = acc * att[hh * 48 + d];
    float vs = acc * att[hh * 48 + 16 + d];
#pragma unroll
    for (int s = 8; s >= 1; s >>= 1) {
        vd += __shfl_xor(vd, s, 64);
        vs += __shfl_xor(vs, s, 64);
    }
    if (d == 0) {
        sd[((size_t)g * NQ + n) * HQ + hh] = vd;
        ss[((size_t)g * NQ + n) * HQ + hh] = vs;
    }
}

// ------ fused: edge-score + softmax + aggregate + ELU + LN (wave per node) ---
// pass 1: lane = edge (global loads once, cache to LDS, head-max reduce)
// pass 2/3: lane = (h, c) over LDS; phase B: lane = output feature j
__global__ void __launch_bounds__(256) k_fused(
        const float* __restrict__ ef, const float* __restrict__ We,
        const float* __restrict__ att,
        const int* __restrict__ offs, const int2* __restrict__ csr2,
        const float* __restrict__ sd, const float* __restrict__ ss,
        const _Float16* __restrict__ hprojH,
        const float* __restrict__ gamma, const float* __restrict__ beta,
        _Float16* __restrict__ alphaH, _Float16* __restrict__ spatialH) {
    __shared__ float Wl[EDQ * GQ];                       // 2KB: We staged
    __shared__ __align__(16) float WA[EDQ * HQ];         // [i][h] factored edge-attn
    __shared__ __align__(16) float ecache[4][CCAP * 4];  // 4KB: score->exp per (edge,h)
    __shared__ half8 eac[4][CCAP];                       // 4KB: ea as f16x8
    __shared__ int   srcs[4][CCAP];                      // 1KB
    __shared__ int   eids[4][CCAP];                      // 1KB
    int t = threadIdx.x;
    for (int i = t; i < EDQ * GQ; i += 256) Wl[i] = We[i];
    if (t < EDQ * HQ) {
        int i = t >> 2, h4 = t & 3;
        float s = 0.f;
#pragma unroll
        for (int d = 0; d < DQ; ++d)
            s = fmaf(We[i * GQ + h4 * DQ + d], att[h4 * 48 + 32 + d], s);
        WA[t] = s;
    }
    __syncthreads();
    int w = t >> 6, lane = t & 63;
    int wid = blockIdx.x * 4 + w;              // exact: grid = NGQ*NQ/4
    int g = wid / NQ, n = wid % NQ;
    int beg = offs[n], deg = offs[n + 1] - beg;
    size_t ebase = (size_t)g * EQ;
    size_t nbase = (size_t)g * NQ;
    float4 sd4 = *(const float4*)&sd[(nbase + n) * HQ];
    // ---- pass 1 (edge-parallel): load once, score all heads, cache ---------
    float mxr[4] = {-1e30f, -1e30f, -1e30f, -1e30f};
    for (int k = lane; k < deg; k += 64) {
        int2 pr = csr2[beg + k];
        float4 ssv = *(const float4*)&ss[(nbase + pr.y) * HQ];
        const float4* eap = (const float4*)(ef + (ebase + pr.x) * EDQ);
        float4 lo = eap[0], hi = eap[1];
        float scv[4];
#pragma unroll
        for (int hh = 0; hh < 4; ++hh) {
            float4 w0 = *(const float4*)&WA[0 * 4];  // broadcast reads; hh-th comp below
            float se;
            {
                // WA[i][hh] reads (same-address broadcast across lanes)
                se =            lo.x * WA[0 * 4 + hh];
                se = fmaf(lo.y, WA[1 * 4 + hh], se);
                se = fmaf(lo.z, WA[2 * 4 + hh], se);
                se = fmaf(lo.w, WA[3 * 4 + hh], se);
                se = fmaf(hi.x, WA[4 * 4 + hh], se);
                se = fmaf(hi.y, WA[5 * 4 + hh], se);
                se = fmaf(hi.z, WA[6 * 4 + hh], se);
                se = fmaf(hi.w, WA[7 * 4 + hh], se);
            }
            (void)w0;
            float sdh = (hh == 0) ? sd4.x : (hh == 1) ? sd4.y : (hh == 2) ? sd4.z : sd4.w;
            float ssh = (hh == 0) ? ssv.x : (hh == 1) ? ssv.y : (hh == 2) ? ssv.z : ssv.w;
            float sc = sdh + ssh + se;
            sc = (sc >= 0.f) ? sc : 0.2f * sc;
            scv[hh] = sc;
            mxr[hh] = fmaxf(mxr[hh], sc);
        }
        if (k < CCAP) {
            *(float4*)&ecache[w][k * 4] = make_float4(scv[0], scv[1], scv[2], scv[3]);
            half8 hv;
            hv[0] = (_Float16)lo.x; hv[1] = (_Float16)lo.y;
            hv[2] = (_Float16)lo.z; hv[3] = (_Float16)lo.w;
            hv[4] = (_Float16)hi.x; hv[5] = (_Float16)hi.y;
            hv[6] = (_Float16)hi.z; hv[7] = (_Float16)hi.w;
            eac[w][k] = hv;
            srcs[w][k] = pr.y;
            eids[w][k] = pr.x;
        }
    }
#pragma unroll
    for (int s = 1; s < 64; s <<= 1) {
#pragma unroll
        for (int hh = 0; hh < 4; ++hh)
            mxr[hh] = fmaxf(mxr[hh], __shfl_xor(mxr[hh], s, 64));
    }
    int h = lane >> 4, c = lane & 15;
    float mxh = (h == 0) ? mxr[0] : (h == 1) ? mxr[1] : (h == 2) ? mxr[2] : mxr[3];
    float sdh = (h == 0) ? sd4.x : (h == 1) ? sd4.y : (h == 2) ? sd4.z : sd4.w;
    // ---- pass 2 (LDS): exp, sum, weighted edge-feature sums ----------------
    float sum = 0.f;
    float ws[8] = {0.f, 0.f, 0.f, 0.f, 0.f, 0.f, 0.f, 0.f};
    for (int k = c; k < deg; k += 16) {
        float e;
        if (k < CCAP) {
            e = __expf(ecache[w][k * 4 + h] - mxh);
            ecache[w][k * 4 + h] = e;
            half8 ev = eac[w][k];
#pragma unroll
            for (int i = 0; i < 8; ++i) ws[i] = fmaf(e, (float)ev[i], ws[i]);
        } else {                               // cold: deg > CCAP
            int2 pr = csr2[beg + k];
            float4 ssv = *(const float4*)&ss[(nbase + pr.y) * HQ];
            float ssh = (h == 0) ? ssv.x : (h == 1) ? ssv.y : (h == 2) ? ssv.z : ssv.w;
            const float4* eap = (const float4*)(ef + (ebase + pr.x) * EDQ);
            float4 lo = eap[0], hi = eap[1];
            float se =      lo.x * WA[0 * 4 + h];
            se = fmaf(lo.y, WA[1 * 4 + h], se); se = fmaf(lo.z, WA[2 * 4 + h], se);
            se = fmaf(lo.w, WA[3 * 4 + h], se); se = fmaf(hi.x, WA[4 * 4 + h], se);
            se = fmaf(hi.y, WA[5 * 4 + h], se); se = fmaf(hi.z, WA[6 * 4 + h], se);
            se = fmaf(hi.w, WA[7 * 4 + h], se);
            float sc = sdh + ssh + se;
            sc = (sc >= 0.f) ? sc : 0.2f * sc;
            e = __expf(sc - mxh);
            ws[0] = fmaf(e, lo.x, ws[0]); ws[1] = fmaf(e, lo.y, ws[1]);
            ws[2] = fmaf(e, lo.z, ws[2]); ws[3] = fmaf(e, lo.w, ws[3]);
            ws[4] = fmaf(e, hi.x, ws[4]); ws[5] = fmaf(e, hi.y, ws[5]);
            ws[6] = fmaf(e, hi.z, ws[6]); ws[7] = fmaf(e, hi.w, ws[7]);
        }
        sum += e;
    }
#pragma unroll
    for (int s = 1; s < 16; s <<= 1) {
        sum += __shfl_xor(sum, s, 16);
#pragma unroll
        for (int i = 0; i < 8; ++i) ws[i] += __shfl_xor(ws[i], s, 16);
    }
    float inv = 1.f / (sum + 1e-16f);
#pragma unroll
    for (int i = 0; i < 8; ++i) ws[i] *= inv;
    // ---- pass 3: write normalized alpha (f16) ------------------------------
    for (int k = c; k < deg; k += 16) {
        float e; int eid;
        if (k < CCAP) {
            e = ecache[w][k * 4 + h];
            eid = eids[w][k];
        } else {
            int2 pr = csr2[beg + k];
            eid = pr.x;
            float4 ssv = *(const float4*)&ss[(nbase + pr.y) * HQ];
            float ssh = (h == 0) ? ssv.x : (h == 1) ? ssv.y : (h == 2) ? ssv.z : ssv.w;
            const float4* eap = (const float4*)(ef + (ebase + pr.x) * EDQ);
            float4 lo = eap[0], hi = eap[1];
            float se =      lo.x * WA[0 * 4 + h];
            se = fmaf(lo.y, WA[1 * 4 + h], se); se = fmaf(lo.z, WA[2 * 4 + h], se);
            se = fmaf(lo.w, WA[3 * 4 + h], se); se = fmaf(hi.x, WA[4 * 4 + h], se);
            se = fmaf(hi.y, WA[5 * 4 + h], se); se = fmaf(hi.z, WA[6 * 4 + h], se);
            se = fmaf(hi.w, WA[7 * 4 + h], se);
            float sc = sdh + ssh + se;
            sc = (sc >= 0.f) ? sc : 0.2f * sc;
            e = __expf(sc - mxh);
        }
        alphaH[(ebase + eid) * HQ + h] = (_Float16)(e * inv);
    }
    // ---- phase B: aggregate alpha*h[src] (f16 gathers), ELU + LN -----------
    int dmain = deg < CCAP ? deg : CCAP;
    float acc = 0.f;
    int k = 0;
    for (; k + 4 <= dmain; k += 4) {
        float e0 = ecache[w][(k + 0) * 4 + h];
        float e1 = ecache[w][(k + 1) * 4 + h];
        float e2 = ecache[w][(k + 2) * 4 + h];
        float e3 = ecache[w][(k + 3) * 4 + h];
        int s0 = srcs[w][k + 0], s1 = srcs[w][k + 1];
        int s2 = srcs[w][k + 2], s3 = srcs[w][k + 3];
        float h0 = (float)hprojH[(nbase + s0) * GQ + lane];
        float h1 = (float)hprojH[(nbase + s1) * GQ + lane];
        float h2 = (float)hprojH[(nbase + s2) * GQ + lane];
        float h3 = (float)hprojH[(nbase + s3) * GQ + lane];
        acc = fmaf(e0, h0, acc); acc = fmaf(e1, h1, acc);
        acc = fmaf(e2, h2, acc); acc = fmaf(e3, h3, acc);
    }
    for (; k < dmain; ++k) {
        float e0 = ecache[w][k * 4 + h];
        float h0 = (float)hprojH[(nbase + srcs[w][k]) * GQ + lane];
        acc = fmaf(e0, h0, acc);
    }
    for (; k < deg; ++k) {                     // cold path
        int2 pr = csr2[beg + k];
        float4 ssv = *(const float4*)&ss[(nbase + pr.y) * HQ];
        float ssh = (h == 0) ? ssv.x : (h == 1) ? ssv.y : (h == 2) ? ssv.z : ssv.w;
        const float4* eap = (const float4*)(ef + (ebase + pr.x) * EDQ);
        float4 lo = eap[0], hi = eap[1];
        float se =      lo.x * WA[0 * 4 + h];
        se = fmaf(lo.y, WA[1 * 4 + h], se); se = fmaf(lo.z, WA[2 * 4 + h], se);
        se = fmaf(lo.w, WA[3 * 4 + h], se); se = fmaf(hi.x, WA[4 * 4 + h], se);
        se = fmaf(hi.y, WA[5 * 4 + h], se); se = fmaf(hi.z, WA[6 * 4 + h], se);
        se = fmaf(hi.w, WA[7 * 4 + h], se);
        float sc = sdh + ssh + se;
        sc = (sc >= 0.f) ? sc : 0.2f * sc;
        float e0 = __expf(sc - mxh);
        float h0 = (float)hprojH[(nbase + pr.y) * GQ + lane];
        acc = fmaf(e0, h0, acc);
    }
    acc *= inv;
    float t2 = 0.f;
#pragma unroll
    for (int i = 0; i < 8; ++i) t2 = fmaf(ws[i], Wl[i * GQ + lane], t2);
    float x = acc + t2;
    x = (x > 0.f) ? x : (__expf(x) - 1.f);     // ELU
    float s1 = x, s2v = x * x;
#pragma unroll
    for (int s = 32; s >= 1; s >>= 1) {
        s1 += __shfl_xor(s1, s, 64);
        s2v += __shfl_xor(s2v, s, 64);
    }
    float mu = s1 * (1.f / 64.f);
    float var = s2v * (1.f / 64.f) - mu * mu;
    float y = (x - mu) * rsqrtf(var + LN_EPSQ) * gamma[lane] + beta[lane];
    spatialH[(nbase + n) * GQ + lane] = (_Float16)y;
}

// -------------------- GRU via MFMA (f16 inputs, f32 accum) -------------------
// block = 32 sequences, 4 waves; wave w owns hidden cols [16w,16w+16)
__device__ inline f32x4 MF(half8 a, half8 b, f32x4 c) {
    return __builtin_amdgcn_mfma_f32_16x16x32_f16(a, b, c, 0, 0, 0);
}

__global__ void __launch_bounds__(256) k_gru(
        const _Float16* __restrict__ xh,     // [48][2000][64] f16 (g = b*12+t)
        const float* __restrict__ Wih, const float* __restrict__ Whh,
        const float* __restrict__ bih, const float* __restrict__ bhh,
        const float* __restrict__ Wout, const float* __restrict__ bout,
        float* __restrict__ out) {
    __shared__ _Float16 hlds[32][72];          // +8 pad: 144B row stride
    __shared__ float pred_s[4][32];
    int tid = threadIdx.x;
    int w = tid >> 6, l = tid & 63;
    int lr = l & 15, lg = l >> 4;
    int j = w * 16 + lr;                       // this lane's hidden/gate column
    half8 wiF[3][2], whF[3][2];
#pragma unroll
    for (int gb = 0; gb < 3; ++gb) {
        int q = gb * 64 + j;
#pragma unroll
        for (int kt = 0; kt < 2; ++kt) {
            const float* p  = Wih + q * 64 + kt * 32 + lg * 8;
            const float* p2 = Whh + q * 64 + kt * 32 + lg * 8;
            half8 a, b;
#pragma unroll
            for (int i = 0; i < 8; ++i) { a[i] = (_Float16)p[i]; b[i] = (_Float16)p2[i]; }
            wiF[gb][kt] = a; whF[gb][kt] = b;
        }
    }
    float br  = bih[j] + bhh[j];
    float bz  = bih[64 + j] + bhh[64 + j];
    float bin = bih[128 + j];
    float bhn = bhh[128 + j];
    float wo  = Wout[j];
    for (int i = tid; i < 32 * 72; i += 256) ((_Float16*)hlds)[i] = (_Float16)0.f;
    int id0 = blockIdx.x * 32;
    const _Float16* xp0; const _Float16* xp1;
    {
        int id = id0 + lr;          int b = id / NQ, n = id - b * NQ;
        xp0 = xh + ((size_t)b * TQ * NQ + n) * GQ + lg * 8;
        int id2 = id0 + 16 + lr;    int b2 = id2 / NQ, n2 = id2 - b2 * NQ;
        xp1 = xh + ((size_t)b2 * TQ * NQ + n2) * GQ + lg * 8;
    }
    half8 xa[2][2];
    xa[0][0] = *(const half8*)xp0; xa[0][1] = *(const half8*)(xp0 + 32);
    xa[1][0] = *(const half8*)xp1; xa[1][1] = *(const half8*)(xp1 + 32);
    float hprev[2][4] = {{0.f,0.f,0.f,0.f},{0.f,0.f,0.f,0.f}};
    __syncthreads();
    for (int t = 0; t < TQ; ++t) {
        f32x4 aR[2], aZ[2], aIN[2], aHN[2];
#pragma unroll
        for (int mt = 0; mt < 2; ++mt) {
            aR[mt]  = (f32x4){br, br, br, br};
            aZ[mt]  = (f32x4){bz, bz, bz, bz};
            aIN[mt] = (f32x4){bin, bin, bin, bin};
            aHN[mt] = (f32x4){bhn, bhn, bhn, bhn};
        }
#pragma unroll
        for (int mt = 0; mt < 2; ++mt)
#pragma unroll
            for (int kt = 0; kt < 2; ++kt) {
                aR[mt]  = MF(xa[mt][kt], wiF[0][kt], aR[mt]);
                aZ[mt]  = MF(xa[mt][kt], wiF[1][kt], aZ[mt]);
                aIN[mt] = MF(xa[mt][kt], wiF[2][kt], aIN[mt]);
            }
        half8 ha[2][2];
#pragma unroll
        for (int mt = 0; mt < 2; ++mt) {
            ha[mt][0] = *(const half8*)&hlds[16 * mt + lr][lg * 8];
            ha[mt][1] = *(const half8*)&hlds[16 * mt + lr][32 + lg * 8];
        }
#pragma unroll
        for (int mt = 0; mt < 2; ++mt)
#pragma unroll
            for (int kt = 0; kt < 2; ++kt) {
                aR[mt]  = MF(ha[mt][kt], whF[0][kt], aR[mt]);
                aZ[mt]  = MF(ha[mt][kt], whF[1][kt], aZ[mt]);
                aHN[mt] = MF(ha[mt][kt], whF[2][kt], aHN[mt]);
            }
        if (t + 1 < TQ) {
            xp0 += (size_t)NQ * GQ; xp1 += (size_t)NQ * GQ;
            xa[0][0] = *(const half8*)xp0; xa[0][1] = *(const half8*)(xp0 + 32);
            xa[1][0] = *(const half8*)xp1; xa[1][1] = *(const half8*)(xp1 + 32);
        }
#pragma unroll
        for (int mt = 0; mt < 2; ++mt)
#pragma unroll
            for (int r4 = 0; r4 < 4; ++r4) {
                float r = 1.f / (1.f + __expf(-aR[mt][r4]));
                float z = 1.f / (1.f + __expf(-aZ[mt][r4]));
                float xg = aIN[mt][r4] + r * aHN[mt][r4];
                float e2 = __expf(2.f * xg);
                float nn = 1.f - 2.f / (e2 + 1.f);     // tanh(xg)
                hprev[mt][r4] = z * (hprev[mt][r4] - nn) + nn;
            }
        __syncthreads();
#pragma unroll
        for (int mt = 0; mt < 2; ++mt)
#pragma unroll
            for (int r4 = 0; r4 < 4; ++r4)
                hlds[16 * mt + 4 * lg + r4][j] = (_Float16)hprev[mt][r4];
        __syncthreads();
    }
    float pv[2][4];
#pragma unroll
    for (int mt = 0; mt < 2; ++mt)
#pragma unroll
        for (int r4 = 0; r4 < 4; ++r4) {
            int id = id0 + 16 * mt + 4 * lg + r4;
            out[8000 + (size_t)id * GHQ + j] = hprev[mt][r4];
            pv[mt][r4] = hprev[mt][r4] * wo;
        }
#pragma unroll
    for (int s = 1; s <= 8; s <<= 1)
#pragma unroll
        for (int mt = 0; mt < 2; ++mt)
#pragma unroll
            for (int r4 = 0; r4 < 4; ++r4)
                pv[mt][r4] += __shfl_xor(pv[mt][r4], s);
    if (lr == 0) {
#pragma unroll
        for (int mt = 0; mt < 2; ++mt)
#pragma unroll
            for (int r4 = 0; r4 < 4; ++r4)
                pred_s[w][16 * mt + 4 * lg + r4] = pv[mt][r4];
    }
    __syncthreads();
    if (tid < 32) {
        float s = pred_s[0][tid] + pred_s[1][tid] + pred_s[2][tid] + pred_s[3][tid] + bout[0];
        out[id0 + tid] = s;
    }
}

// -------------------- attention mean over batch (f16 in) ---------------------
__global__ void k_attn(const _Float16* __restrict__ alpha, float* __restrict__ out) {
    int gid = blockIdx.x * blockDim.x + threadIdx.x;   // t*EQ + e
    if (gid >= TQ * EQ) return;
    int tt = gid / EQ, e = gid % EQ;
    float a0 = 0.f, a1 = 0.f, a2 = 0.f, a3 = 0.f;
#pragma unroll
    for (int b = 0; b < BQ; ++b) {
        half4v v = *(const half4v*)&alpha[(((size_t)b * TQ + tt) * EQ + e) * HQ];
        a0 += (float)v[0]; a1 += (float)v[1]; a2 += (float)v[2]; a3 += (float)v[3];
    }
    float4 r = {a0 * 0.25f, a1 * 0.25f, a2 * 0.25f, a3 * 0.25f};
    *(float4*)&out[520000 + (size_t)gid * HQ] = r;     // pred(8000)+h_i(512000)
}

extern "C" void kernel_launch(void* const* d_in, const int* in_sizes, int n_in,
                              void* d_out, int out_size, void* d_ws, size_t ws_size,
                              hipStream_t stream) {
    const float* nodef = (const float*)d_in[0];
    const float* edgef = (const float*)d_in[1];
    const float* Wn    = (const float*)d_in[2];
    const float* We    = (const float*)d_in[3];
    const float* att   = (const float*)d_in[4];
    const float* gamma = (const float*)d_in[5];
    const float* beta  = (const float*)d_in[6];
    const float* Wih   = (const float*)d_in[7];
    const float* Whh   = (const float*)d_in[8];
    const float* bih   = (const float*)d_in[9];
    const float* bhh   = (const float*)d_in[10];
    const float* Wout  = (const float*)d_in[11];
    const float* bout  = (const float*)d_in[12];
    const int*   ei    = (const int*)d_in[13];

    char* ws = (char*)d_ws;
    size_t o = 0;
    int*  count  = (int*)(ws + o);  o += 2048 * 4;
    int*  offs   = (int*)(ws + o);  o += 2048 * 4;
    int*  cursor = (int*)(ws + o);  o += 2048 * 4;
    int2* csr2   = (int2*)(ws + o); o += (size_t)EQ * 8;
    float* sd      = (float*)(ws + o); o += (size_t)NGQ * NQ * HQ * 4;
    float* ss      = (float*)(ws + o); o += (size_t)NGQ * NQ * HQ * 4;
    _Float16* hprojH   = (_Float16*)(ws + o); o += (size_t)NGQ * NQ * GQ * 2;
    _Float16* alphaH   = (_Float16*)(ws + o); o += (size_t)NGQ * EQ * HQ * 2;
    _Float16* spatialH = (_Float16*)(ws + o); o += (size_t)NGQ * NQ * GQ * 2;

    hipMemsetAsync(count, 0, NQ * sizeof(int), stream);
    k_count  <<<(EQ + 255) / 256, 256, 0, stream>>>(ei, count);
    k_scan   <<<1, 1024, 0, stream>>>(count, offs, cursor);
    k_scatter<<<(EQ + 255) / 256, 256, 0, stream>>>(ei, cursor, csr2);

    k_nodeproj<<<(NGQ * NQ * 64) / 256, 256, 0, stream>>>(nodef, Wn, att, hprojH, sd, ss);
    k_fused   <<<(NGQ * NQ) / 4, 256, 0, stream>>>(edgef, We, att, offs, csr2,
                                                   sd, ss, hprojH, gamma, beta,
                                                   alphaH, spatialH);
    k_gru     <<<(BQ * NQ) / 32, 256, 0, stream>>>(spatialH, Wih, Whh, bih, bhh,
                                                   Wout, bout, (float*)d_out);
    k_attn    <<<(TQ * EQ + 255) / 256, 256, 0, stream>>>(alphaH, (float*)d_out);
}